// Round 16
// baseline (127.106 us; speedup 1.0000x reference)
//
#include <hip/hip_runtime.h>
#include <math.h>

#define Hd 128
#define Rr 3
#define Ll 4
#define NPW 16   // nodes (M-rows) per wave
#define NW  8    // waves per block (512 threads)
#define SRP 136  // Sr row pitch in bf16 elems (272 B, 16-B aligned)

typedef float f32x4 __attribute__((ext_vector_type(4)));
typedef short s16x8 __attribute__((ext_vector_type(8)));

__device__ __forceinline__ unsigned short f2bf(float f){
    unsigned u = __float_as_uint(f);
    return (unsigned short)((u + 0x7FFFu + ((u >> 16) & 1u)) >> 16);
}
__device__ __forceinline__ float bf2f(unsigned short h){
    return __uint_as_float(((unsigned)h) << 16);
}
__device__ __forceinline__ s16x8 cvt8(const float* p){
    float4 a = *(const float4*)p;
    float4 b = *(const float4*)(p + 4);
    float v[8] = {a.x, a.y, a.z, a.w, b.x, b.y, b.z, b.w};
    s16x8 r;
    #pragma unroll
    for (int j = 0; j < 8; ++j) r[j] = (short)f2bf(v[j]);
    return r;
}
__device__ __forceinline__ int lower_bound_i32(const int* __restrict__ a, int n, int key){
    int lo = 0, hi = n;
    while (lo < hi){
        int mid = (lo + hi) >> 1;
        if (a[mid] < key) lo = mid + 1; else hi = mid;
    }
    return lo;
}
__device__ __forceinline__ void gload_lds16(const unsigned short* g, unsigned short* l){
    __builtin_amdgcn_global_load_lds(
        (const __attribute__((address_space(1))) void*)g,
        (__attribute__((address_space(3))) void*)l, 16, 0, 0);
}
// unpack element i (0..3) of a D-layout bf16 pair-packed uint2
__device__ __forceinline__ float gxel(uint2 u, int i){
    unsigned w = (i < 2) ? u.x : u.y;
    return bf2f((unsigned short)((i & 1) ? (w >> 16) : (w & 0xffff)));
}

// ---- McT = out_w @ wv (folded), bc = out_w @ bv + out_b  (verified r1-r15) ----
__global__ void fold_proj_kernel(const float* __restrict__ in_proj_w,
                                 const float* __restrict__ in_proj_b,
                                 const float* __restrict__ out_w,
                                 const float* __restrict__ out_b,
                                 float* __restrict__ McT,
                                 float* __restrict__ bc)
{
    const int i = blockIdx.x;
    const int j = threadIdx.x;
    float acc = 0.f;
    for (int k = 0; k < Hd; ++k)
        acc = fmaf(out_w[j * Hd + k], in_proj_w[(2 * Hd + k) * Hd + i], acc);
    McT[i * Hd + j] = acc;
    if (i == 0){
        float b = out_b[j];
        for (int k = 0; k < Hd; ++k)
            b = fmaf(out_w[j * Hd + k], in_proj_b[2 * Hd + k], b);
        bc[j] = b;
    }
}

// ---- quantize weights to bf16 MFMA B-fragments (verified r4-r15) ----
__global__ void pack_kernel(const float* __restrict__ r_whh, const float* __restrict__ u_whh,
                            const float* __restrict__ r_wxh, const float* __restrict__ u_wxh,
                            const float* __restrict__ c_whh, const float* __restrict__ c_wxh,
                            const float* __restrict__ McT,
                            unsigned short* __restrict__ whi)
{
    const int mat  = blockIdx.y;
    const int tile = blockIdx.x;
    const int l    = threadIdx.x;
    const float* W;
    switch (mat){
        case 0: W = r_whh; break;  case 1: W = u_whh; break;
        case 2: W = r_wxh; break;  case 3: W = u_wxh; break;
        case 4: W = c_whh; break;  case 5: W = c_wxh; break;
        default: W = McT;
    }
    const int kc = tile >> 3, nc = tile & 7;
    const int kbase = kc * 32 + (l >> 4) * 8;
    const int n = nc * 16 + (l & 15);
    const size_t obase = ((size_t)(mat * 32 + tile) * 64 + l) * 8;
    #pragma unroll
    for (int j = 0; j < 8; ++j)
        whi[obase + j] = f2bf(W[(kbase + j) * Hd + n]);
}

#define MM1(acc, AH, BH)                                                  \
    acc = __builtin_amdgcn_mfma_f32_16x16x32_bf16(AH, BH, acc, 0, 0, 0);

// ================= gx precompute (double-buffered): gx[g,t,node] = x@Wx_g + b_g =================
__global__ __launch_bounds__(512, 1) void gx_kernel(
    const float* __restrict__ x_rank,
    const float* __restrict__ r_b, const float* __restrict__ u_b, const float* __restrict__ c_b,
    const unsigned short* __restrict__ whi,
    uint2* __restrict__ gx, int N, int NT)
{
    __shared__ __align__(16) unsigned short WX[2][16384];   // 64 KB -> 2 blocks/CU
    const int tid = threadIdx.x;
    const int wid = tid >> 6;
    const int l   = tid & 63;
    const int lr  = l & 15;
    const int lg  = l >> 4;

    #define STAGE_X(mat, b)                                                      \
        {                                                                        \
            const unsigned short* msrc = whi + (size_t)(mat) * 16384;            \
            _Pragma("unroll")                                                    \
            for (int it = 0; it < 4; ++it){                                      \
                const int chunk = it * 8 + wid;                                  \
                gload_lds16(msrc + chunk * 512 + l * 8, &WX[b][chunk * 512]);    \
            }                                                                    \
        }

    STAGE_X(2, 0);                      // r_wxh -> buf0

    const int u = blockIdx.x * NW + wid;
    const int valid = (u < 3 * NT);
    const int uu = valid ? u : 3 * NT - 1;
    const int t  = uu / NT;
    const int nt = uu % NT;

    int nn = nt * NPW + lr; if (nn > N - 1) nn = N - 1;
    const float* xp = x_rank + ((size_t)nn * Rr + t) * Hd;
    s16x8 xh[4];
    #pragma unroll
    for (int kc = 0; kc < 4; ++kc)
        xh[kc] = cvt8(xp + kc * 32 + lg * 8);

    #define GX_COMP(g, b, bp)                                                    \
        {                                                                        \
            _Pragma("unroll")                                                    \
            for (int nc = 0; nc < 8; ++nc){                                      \
                f32x4 acc = (f32x4){0.f, 0.f, 0.f, 0.f};                         \
                _Pragma("unroll")                                                \
                for (int kc = 0; kc < 4; ++kc){                                  \
                    s16x8 bb = *(const s16x8*)&WX[b][(((kc) * 8 + nc) * 64 + l) * 8]; \
                    MM1(acc, xh[kc], bb);                                        \
                }                                                                \
                const float bv = bp[nc * 16 + lr];                               \
                uint2 o;                                                         \
                o.x = ((unsigned)f2bf(acc[1] + bv) << 16) | f2bf(acc[0] + bv);   \
                o.y = ((unsigned)f2bf(acc[3] + bv) << 16) | f2bf(acc[2] + bv);   \
                if (valid)                                                       \
                    gx[(((size_t)((g) * Rr + t) * NT + nt) * 8 + nc) * 64 + l] = o; \
                if ((nc & 3) == 3) __builtin_amdgcn_sched_barrier(0);            \
            }                                                                    \
        }

    __syncthreads();           // buf0 ready
    STAGE_X(3, 1);             // u_wxh -> buf1
    GX_COMP(0, 0, r_b);
    __syncthreads();           // buf1 ready; buf0 readers done
    STAGE_X(5, 0);             // c_wxh -> buf0
    GX_COMP(1, 1, u_b);
    __syncthreads();           // buf0 ready
    GX_COMP(2, 0, c_b);
    #undef GX_COMP
    #undef STAGE_X
}

// ================= 7-phase recurrent kernel (triple-buffered WL, fused R/Z) =================
#define BF3(b, kc, nc) (*(const s16x8*)&WL[b][(((kc) * 8 + (nc)) * 64 + l) * 8])
#define GXLD(g, t, nc) gx[(((size_t)((g) * Rr + (t)) * NT + gtile) * 8 + (nc)) * 64 + l]

__global__ __launch_bounds__(512, 1) void gru_rec7_kernel(
    const int* __restrict__ valid_idx, int nv,
    const unsigned short* __restrict__ whi,
    const uint2* __restrict__ gx,
    const float* __restrict__ bc,
    float* __restrict__ out, int N, int NT)
{
    __shared__ __align__(16) unsigned short WL[3][16384];        // 96 KB triple buffer
    __shared__ __align__(16) unsigned short Sr_all[NW][NPW][SRP]; // 34.8 KB bf16
    __shared__ int lo_all[NW][NPW];
    __shared__ int hi_all[NW][NPW];

    const int tid = threadIdx.x;
    const int wid = tid >> 6;
    const int l   = tid & 63;
    const int lr  = l & 15;
    const int lg  = l >> 4;
    const int wtile = blockIdx.x * NW + wid;
    const int n0  = wtile * NPW;
    const int gtile = (wtile < NT) ? wtile : NT - 1;   // OOB waves clamp; rows never stored

    unsigned short (*Sr)[SRP] = Sr_all[wid];
    int* loL = lo_all[wid];
    int* hiL = hi_all[wid];

    #define STAGE_MAT(mat, b)                                                    \
        {                                                                        \
            const unsigned short* msrc = whi + (size_t)(mat) * 16384;            \
            _Pragma("unroll")                                                    \
            for (int it = 0; it < 4; ++it){                                      \
                const int chunk = it * 8 + wid;                                  \
                gload_lds16(msrc + chunk * 512 + l * 8, &WL[b][chunk * 512]);    \
            }                                                                    \
        }

    #define LOHI(T)                                                              \
        if (l < NPW){                                                            \
            int n = n0 + l, lo = 0, hi = 0;                                      \
            if (n < N){                                                          \
                int F = (n * Rr + (T)) * Ll;                                     \
                lo = lower_bound_i32(valid_idx, nv, F);                          \
                hi = lower_bound_i32(valid_idx, nv, F + Ll);                     \
            }                                                                    \
            loL[l] = lo; hiL[l] = hi;                                            \
        }

    f32x4 hD[8], zD[8];
    s16x8 ah[4];
    uint2 gc8[8];
    float obc[8];
    #pragma unroll
    for (int nc = 0; nc < 8; ++nc) obc[nc] = bc[nc * 16 + lr];

    // prologue: stage McT, r_whh, u_whh into the three buffers
    STAGE_MAT(6, 0);
    STAGE_MAT(0, 1);
    STAGE_MAT(1, 2);

    // t0 (h0 = 0): h1 = sig(gxu)*tanh(gxc)  — pure VALU, overlaps stage fills
    LOHI(0)
    {
        uint2 gu0[8];
        #pragma unroll
        for (int nc = 0; nc < 8; ++nc){ gu0[nc] = GXLD(1, 0, nc); gc8[nc] = GXLD(2, 0, nc); }
        #pragma unroll
        for (int nc = 0; nc < 8; ++nc){
            #pragma unroll
            for (int i = 0; i < 4; ++i){
                float z = 1.f / (1.f + __expf(-gxel(gu0[nc], i)));
                float e = __expf(2.f * gxel(gc8[nc], i));
                float c = 1.f - 2.f / (e + 1.f);
                float hn = z * c;
                hD[nc][i] = hn;
                Sr[lg * 4 + i][nc * 16 + lr] = f2bf(hn);
            }
        }
        #pragma unroll
        for (int kc = 0; kc < 4; ++kc)
            ah[kc] = *(const s16x8*)&Sr[lr][kc * 32 + lg * 8];
    }

    // fused R/Z phase: accR from BR, accZ from BZ (both resident)
    #define P1_PHASE(T, BR, BZ)                                                  \
        {                                                                        \
            LOHI(T)                                                              \
            uint2 gr[8], gu[8];                                                  \
            _Pragma("unroll")                                                    \
            for (int nc = 0; nc < 8; ++nc){                                      \
                gr[nc] = GXLD(0, T, nc); gu[nc] = GXLD(1, T, nc);                \
                gc8[nc] = GXLD(2, T, nc);                                        \
            }                                                                    \
            _Pragma("unroll")                                                    \
            for (int nc = 0; nc < 8; ++nc){                                      \
                f32x4 aR = (f32x4){0.f, 0.f, 0.f, 0.f};                          \
                f32x4 aZ = (f32x4){0.f, 0.f, 0.f, 0.f};                          \
                _Pragma("unroll")                                                \
                for (int kc = 0; kc < 4; ++kc){ s16x8 b = BF3(BR, kc, nc); MM1(aR, ah[kc], b); } \
                _Pragma("unroll")                                                \
                for (int kc = 0; kc < 4; ++kc){ s16x8 b = BF3(BZ, kc, nc); MM1(aZ, ah[kc], b); } \
                _Pragma("unroll")                                                \
                for (int i = 0; i < 4; ++i){                                     \
                    float r = 1.f / (1.f + __expf(-(aR[i] + gxel(gr[nc], i))));  \
                    Sr[lg * 4 + i][nc * 16 + lr] = f2bf(r * hD[nc][i]);          \
                    zD[nc][i] = 1.f / (1.f + __expf(-(aZ[i] + gxel(gu[nc], i)))); \
                }                                                                \
                if (nc & 1) __builtin_amdgcn_sched_barrier(0);                   \
            }                                                                    \
        }

    #define P2_PHASE(BC)                                                         \
        {                                                                        \
            s16x8 rhh[4];                                                        \
            _Pragma("unroll")                                                    \
            for (int kc = 0; kc < 4; ++kc)                                       \
                rhh[kc] = *(const s16x8*)&Sr[lr][kc * 32 + lg * 8];              \
            _Pragma("unroll")                                                    \
            for (int nc = 0; nc < 8; ++nc){                                      \
                f32x4 aC = (f32x4){0.f, 0.f, 0.f, 0.f};                          \
                _Pragma("unroll")                                                \
                for (int kc = 0; kc < 4; ++kc){ s16x8 b = BF3(BC, kc, nc); MM1(aC, rhh[kc], b); } \
                _Pragma("unroll")                                                \
                for (int i = 0; i < 4; ++i){                                     \
                    float e = __expf(2.f * (aC[i] + gxel(gc8[nc], i)));          \
                    float c = 1.f - 2.f / (e + 1.f);                             \
                    float ho = hD[nc][i];                                        \
                    float hn = ho + zD[nc][i] * (c - ho);                        \
                    hD[nc][i] = hn;                                              \
                    Sr[lg * 4 + i][nc * 16 + lr] = f2bf(hn);                     \
                }                                                                \
                if ((nc & 3) == 3) __builtin_amdgcn_sched_barrier(0);            \
            }                                                                    \
            _Pragma("unroll")                                                    \
            for (int kc = 0; kc < 4; ++kc)                                       \
                ah[kc] = *(const s16x8*)&Sr[lr][kc * 32 + lg * 8];               \
        }

    #define O_PHASE(BO)                                                          \
        {                                                                        \
            _Pragma("unroll")                                                    \
            for (int nc = 0; nc < 8; ++nc){                                      \
                f32x4 ao = (f32x4){0.f, 0.f, 0.f, 0.f};                          \
                _Pragma("unroll")                                                \
                for (int kc = 0; kc < 4; ++kc){ s16x8 b = BF3(BO, kc, nc); MM1(ao, ah[kc], b); } \
                _Pragma("unroll")                                                \
                for (int i = 0; i < 4; ++i)                                      \
                    Sr[lg * 4 + i][nc * 16 + lr] = f2bf(ao[i] + obc[nc]);        \
                if ((nc & 3) == 3) __builtin_amdgcn_sched_barrier(0);            \
            }                                                                    \
            _Pragma("unroll")                                                    \
            for (int m = 0; m < 8; ++m){                                         \
                const int row = m * 2 + (l >> 5);                                \
                const int c4  = (l & 31) * 4;                                    \
                const uint2 u2 = *(const uint2*)&Sr[row][c4];                    \
                float4 v = { bf2f((unsigned short)(u2.x & 0xffff)),              \
                             bf2f((unsigned short)(u2.x >> 16)),                 \
                             bf2f((unsigned short)(u2.y & 0xffff)),              \
                             bf2f((unsigned short)(u2.y >> 16)) };               \
                const int lo = loL[row], hi = hiL[row];                          \
                for (int rr = lo; rr < hi; ++rr)                                 \
                    *(float4*)(out + (size_t)rr * Hd + c4) = v;                  \
            }                                                                    \
        }

    // 7-phase schedule; every stage issued >= 1 full phase before first read
    __syncthreads();                         // SYNC1: McT/r_whh/u_whh ready
    O_PHASE(0)                               // t0-O from McT(b0)
    __syncthreads();                         // SYNC2
    STAGE_MAT(4, 0);                         // c_whh -> b0
    P1_PHASE(1, 1, 2)                        // t1 R/Z from r_whh(b1), u_whh(b2)
    __syncthreads();                         // SYNC3
    STAGE_MAT(6, 1);                         // McT -> b1
    P2_PHASE(0)                              // t1 C from c_whh(b0)
    __syncthreads();                         // SYNC4
    STAGE_MAT(0, 2);                         // r_whh -> b2 (t2)
    STAGE_MAT(1, 0);                         // u_whh -> b0 (t2)
    O_PHASE(1)                               // t1-O from McT(b1)
    __syncthreads();                         // SYNC5
    STAGE_MAT(4, 1);                         // c_whh -> b1
    P1_PHASE(2, 2, 0)                        // t2 R/Z
    __syncthreads();                         // SYNC6
    STAGE_MAT(6, 2);                         // McT -> b2
    P2_PHASE(1)                              // t2 C
    __syncthreads();                         // SYNC7
    O_PHASE(2)                               // t2-O from McT(b2)

    #undef O_PHASE
    #undef P2_PHASE
    #undef P1_PHASE
    #undef LOHI
    #undef STAGE_MAT
}

// ================= fallback: round-9 kernel (used if ws_size too small) =================
#define BF_LDS(kc, nc) (*(const s16x8*)&WL[cur][(((kc) * 8 + (nc)) * 64 + l) * 8])
__global__ __launch_bounds__(512, 1) void gru_mfma_fb(
    const float* __restrict__ x_rank,
    const int* __restrict__ valid_idx, int nv,
    const float* __restrict__ r_b, const float* __restrict__ u_b, const float* __restrict__ c_b,
    const unsigned short* __restrict__ whi,
    const float* __restrict__ bc,
    float* __restrict__ out, int N)
{
    __shared__ __align__(16) unsigned short WL[2][16384];
    __shared__ __align__(16) float Sr_all[NW][NPW][132];
    __shared__ float bias_s[4][Hd];
    __shared__ int lo_all[NW][NPW];
    __shared__ int hi_all[NW][NPW];

    const int tid = threadIdx.x;
    const int wid = tid >> 6;
    const int l   = tid & 63;
    const int lr  = l & 15;
    const int lg  = l >> 4;
    const int n0  = (blockIdx.x * NW + wid) * NPW;

    float (*Sr)[132] = Sr_all[wid];
    int* loL = lo_all[wid];
    int* hiL = hi_all[wid];

    if (tid < Hd){
        bias_s[0][tid] = r_b[tid];
        bias_s[1][tid] = u_b[tid];
        bias_s[2][tid] = c_b[tid];
        bias_s[3][tid] = bc[tid];
    }
    #define STAGE_MAT(mat, b)                                                    \
        {                                                                        \
            const unsigned short* msrc = whi + (size_t)(mat) * 16384;            \
            _Pragma("unroll")                                                    \
            for (int it = 0; it < 4; ++it){                                      \
                const int chunk = it * 8 + wid;                                  \
                gload_lds16(msrc + chunk * 512 + l * 8, &WL[b][chunk * 512]);    \
            }                                                                    \
        }
    f32x4 hD[8];
    s16x8 ah[4];
    #pragma unroll
    for (int nc = 0; nc < 8; ++nc) hD[nc] = (f32x4){0.f, 0.f, 0.f, 0.f};
    #pragma unroll
    for (int kc = 0; kc < 4; ++kc) ah[kc] = (s16x8)0;
    s16x8 xh[4], rhh[4];

    unsigned cur = 0;
    STAGE_MAT(0, 0);

    #pragma unroll 1
    for (int t = 0; t < Rr; ++t){
        if (l < NPW){
            int n = n0 + l, lo = 0, hi = 0;
            if (n < N){
                int F = (n * Rr + t) * Ll;
                lo = lower_bound_i32(valid_idx, nv, F);
                hi = lower_bound_i32(valid_idx, nv, F + Ll);
            }
            loL[l] = lo; hiL[l] = hi;
        }
        {
            int nn = n0 + lr; if (nn > N - 1) nn = N - 1;
            const float* xp = x_rank + ((size_t)nn * Rr + t) * Hd;
            #pragma unroll
            for (int kc = 0; kc < 4; ++kc)
                xh[kc] = cvt8(xp + kc * 32 + lg * 8);
        }
        f32x4 accR[8], accZ[8];
        __syncthreads();
        STAGE_MAT(2, cur ^ 1);
        #pragma unroll
        for (int nc = 0; nc < 8; ++nc){
            accR[nc] = (f32x4){0.f, 0.f, 0.f, 0.f};
            #pragma unroll
            for (int kc = 0; kc < 4; ++kc){ s16x8 b = BF_LDS(kc, nc); MM1(accR[nc], ah[kc], b); }
            if ((nc & 3) == 3) __builtin_amdgcn_sched_barrier(0);
        }
        cur ^= 1;
        __syncthreads();
        STAGE_MAT(1, cur ^ 1);
        #pragma unroll
        for (int nc = 0; nc < 8; ++nc){
            #pragma unroll
            for (int kc = 0; kc < 4; ++kc){ s16x8 b = BF_LDS(kc, nc); MM1(accR[nc], xh[kc], b); }
            const float rbc = bias_s[0][nc * 16 + lr];
            #pragma unroll
            for (int i = 0; i < 4; ++i){
                float r = 1.f / (1.f + __expf(-(accR[nc][i] + rbc)));
                Sr[lg * 4 + i][nc * 16 + lr] = r * hD[nc][i];
            }
            if ((nc & 3) == 3) __builtin_amdgcn_sched_barrier(0);
        }
        cur ^= 1;
        __syncthreads();
        STAGE_MAT(3, cur ^ 1);
        #pragma unroll
        for (int nc = 0; nc < 8; ++nc){
            accZ[nc] = (f32x4){0.f, 0.f, 0.f, 0.f};
            #pragma unroll
            for (int kc = 0; kc < 4; ++kc){ s16x8 b = BF_LDS(kc, nc); MM1(accZ[nc], ah[kc], b); }
            if ((nc & 3) == 3) __builtin_amdgcn_sched_barrier(0);
        }
        cur ^= 1;
        __syncthreads();
        STAGE_MAT(4, cur ^ 1);
        #pragma unroll
        for (int nc = 0; nc < 8; ++nc){
            #pragma unroll
            for (int kc = 0; kc < 4; ++kc){ s16x8 b = BF_LDS(kc, nc); MM1(accZ[nc], xh[kc], b); }
            const float ubc = bias_s[1][nc * 16 + lr];
            #pragma unroll
            for (int i = 0; i < 4; ++i)
                accZ[nc][i] = 1.f / (1.f + __expf(-(accZ[nc][i] + ubc)));
            if ((nc & 3) == 3) __builtin_amdgcn_sched_barrier(0);
        }
        cur ^= 1;
        __syncthreads();
        STAGE_MAT(5, cur ^ 1);
        #pragma unroll
        for (int kc = 0; kc < 4; ++kc)
            rhh[kc] = cvt8(&Sr[lr][kc * 32 + lg * 8]);
        f32x4 accC[8];
        #pragma unroll
        for (int nc = 0; nc < 8; ++nc){
            accC[nc] = (f32x4){0.f, 0.f, 0.f, 0.f};
            #pragma unroll
            for (int kc = 0; kc < 4; ++kc){ s16x8 b = BF_LDS(kc, nc); MM1(accC[nc], rhh[kc], b); }
            if ((nc & 3) == 3) __builtin_amdgcn_sched_barrier(0);
        }
        cur ^= 1;
        __syncthreads();
        STAGE_MAT(6, cur ^ 1);
        #pragma unroll
        for (int nc = 0; nc < 8; ++nc){
            #pragma unroll
            for (int kc = 0; kc < 4; ++kc){ s16x8 b = BF_LDS(kc, nc); MM1(accC[nc], xh[kc], b); }
            const float cbc = bias_s[2][nc * 16 + lr];
            #pragma unroll
            for (int i = 0; i < 4; ++i){
                float e = __expf(2.f * (accC[nc][i] + cbc));
                float c = 1.f - 2.f / (e + 1.f);
                float ho = hD[nc][i];
                float hn = ho + accZ[nc][i] * (c - ho);
                hD[nc][i] = hn;
                Sr[lg * 4 + i][nc * 16 + lr] = hn;
            }
            if ((nc & 3) == 3) __builtin_amdgcn_sched_barrier(0);
        }
        #pragma unroll
        for (int kc = 0; kc < 4; ++kc)
            ah[kc] = cvt8(&Sr[lr][kc * 32 + lg * 8]);
        cur ^= 1;
        __syncthreads();
        if (t < Rr - 1) STAGE_MAT(0, cur ^ 1);
        #pragma unroll
        for (int nc = 0; nc < 8; ++nc){
            f32x4 ao = (f32x4){0.f, 0.f, 0.f, 0.f};
            #pragma unroll
            for (int kc = 0; kc < 4; ++kc){ s16x8 b = BF_LDS(kc, nc); MM1(ao, ah[kc], b); }
            const float obc = bias_s[3][nc * 16 + lr];
            #pragma unroll
            for (int i = 0; i < 4; ++i)
                Sr[lg * 4 + i][nc * 16 + lr] = ao[i] + obc;
            if ((nc & 3) == 3) __builtin_amdgcn_sched_barrier(0);
        }
        #pragma unroll
        for (int m = 0; m < 8; ++m){
            const int row = m * 2 + (l >> 5);
            const int c4  = (l & 31) * 4;
            const float4 v = *(const float4*)&Sr[row][c4];
            const int lo = loL[row], hi = hiL[row];
            for (int rr = lo; rr < hi; ++rr)
                *(float4*)(out + (size_t)rr * Hd + c4) = v;
        }
        cur ^= 1;
    }
    #undef STAGE_MAT
}

__global__ void he_order_kernel(const int* __restrict__ he_order,
                                float* __restrict__ out_tail, int nv)
{
    const int i = blockIdx.x * 256 + threadIdx.x;
    if (i < nv) out_tail[i] = (float)he_order[i];
}

extern "C" void kernel_launch(void* const* d_in, const int* in_sizes, int n_in,
                              void* d_out, int out_size, void* d_ws, size_t ws_size,
                              hipStream_t stream)
{
    const float* x_rank    = (const float*)d_in[0];
    // d_in[1] he_features, d_in[2] he_idx: dead (softmax over singleton axis == 1)
    const int*   valid_idx = (const int*)d_in[3];
    const int*   he_order  = (const int*)d_in[4];
    const float* r_whh = (const float*)d_in[5];
    const float* r_wxh = (const float*)d_in[6];
    const float* r_b   = (const float*)d_in[7];
    const float* u_whh = (const float*)d_in[8];
    const float* u_wxh = (const float*)d_in[9];
    const float* u_b   = (const float*)d_in[10];
    const float* c_whh = (const float*)d_in[11];
    const float* c_wxh = (const float*)d_in[12];
    const float* c_b   = (const float*)d_in[13];
    const float* in_proj_w = (const float*)d_in[14];
    const float* in_proj_b = (const float*)d_in[15];
    const float* out_w     = (const float*)d_in[16];
    const float* out_b     = (const float*)d_in[17];

    const int nv = in_sizes[3];
    const int N  = in_sizes[0] / (Rr * Hd);
    const int NT = (N + NPW - 1) / NPW;   // 1875

    // workspace layout
    float* McT = (float*)d_ws;                           // 16384 f32
    float* bc  = McT + Hd * Hd;                          // 128 f32
    unsigned short* whi = (unsigned short*)(bc + Hd);    // 7*16384 u16
    const size_t base = 16384*4 + 128*4 + 7*16384*2;     // 295424 B
    uint2* gx = (uint2*)((char*)d_ws + base);
    const size_t gx_bytes = (size_t)9 * NT * 8 * 64 * 8; // 69.12 MB

    float* out_f    = (float*)d_out;
    float* out_tail = out_f + (size_t)nv * Hd;

    fold_proj_kernel<<<Hd, Hd, 0, stream>>>(in_proj_w, in_proj_b, out_w, out_b, McT, bc);
    pack_kernel<<<dim3(32, 7), 64, 0, stream>>>(r_whh, u_whh, r_wxh, u_wxh, c_whh, c_wxh,
                                                McT, whi);

    const int nodes_per_block = NW * NPW;  // 128
    const int nblocks = (N + nodes_per_block - 1) / nodes_per_block;  // 235

    if (ws_size >= base + gx_bytes){
        const int gxblocks = (3 * NT + NW - 1) / NW;   // 704
        gx_kernel<<<gxblocks, 512, 0, stream>>>(x_rank, r_b, u_b, c_b, whi, gx, N, NT);
        gru_rec7_kernel<<<nblocks, 512, 0, stream>>>(valid_idx, nv, whi, gx, bc, out_f, N, NT);
    } else {
        gru_mfma_fb<<<nblocks, 512, 0, stream>>>(
            x_rank, valid_idx, nv, r_b, u_b, c_b, whi, bc, out_f, N);
    }

    he_order_kernel<<<(nv + 255) / 256, 256, 0, stream>>>(he_order, out_tail, nv);
}

// Round 17
// 120.540 us; speedup vs baseline: 1.0545x; 1.0545x over previous
//
#include <hip/hip_runtime.h>
#include <math.h>

#define Hd 128
#define Rr 3
#define Ll 4
#define NPW 16   // nodes (M-rows) per wave
#define NW  8    // waves per block (512 threads)

typedef float f32x4 __attribute__((ext_vector_type(4)));
typedef short s16x8 __attribute__((ext_vector_type(8)));

__device__ __forceinline__ unsigned short f2bf(float f){
    unsigned u = __float_as_uint(f);
    return (unsigned short)((u + 0x7FFFu + ((u >> 16) & 1u)) >> 16);
}
__device__ __forceinline__ float bf2f(unsigned short h){
    return __uint_as_float(((unsigned)h) << 16);
}
__device__ __forceinline__ s16x8 cvt8(const float* p){
    float4 a = *(const float4*)p;
    float4 b = *(const float4*)(p + 4);
    float v[8] = {a.x, a.y, a.z, a.w, b.x, b.y, b.z, b.w};
    s16x8 r;
    #pragma unroll
    for (int j = 0; j < 8; ++j) r[j] = (short)f2bf(v[j]);
    return r;
}
__device__ __forceinline__ int lower_bound_i32(const int* __restrict__ a, int n, int key){
    int lo = 0, hi = n;
    while (lo < hi){
        int mid = (lo + hi) >> 1;
        if (a[mid] < key) lo = mid + 1; else hi = mid;
    }
    return lo;
}
__device__ __forceinline__ void gload_lds16(const unsigned short* g, unsigned short* l){
    __builtin_amdgcn_global_load_lds(
        (const __attribute__((address_space(1))) void*)g,
        (__attribute__((address_space(3))) void*)l, 16, 0, 0);
}
// unpack element i (0..3) of a D-layout bf16 pair-packed uint2
__device__ __forceinline__ float gxel(uint2 u, int i){
    unsigned w = (i < 2) ? u.x : u.y;
    return bf2f((unsigned short)((i & 1) ? (w >> 16) : (w & 0xffff)));
}

// ---- pack: quantize weights to bf16 B-frags; mat6 = FUSED fold (McT); mat7 = bc ----
// frag elem j of lane l at (mat,kc,nc):  W[kc*32 + (l>>4)*8 + j][nc*16 + (l&15)]
__global__ void pack_kernel(const float* __restrict__ r_whh, const float* __restrict__ u_whh,
                            const float* __restrict__ r_wxh, const float* __restrict__ u_wxh,
                            const float* __restrict__ c_whh, const float* __restrict__ c_wxh,
                            const float* __restrict__ in_proj_w, const float* __restrict__ in_proj_b,
                            const float* __restrict__ out_w, const float* __restrict__ out_b,
                            unsigned short* __restrict__ whi, float* __restrict__ bc)
{
    const int mat  = blockIdx.y;   // 0..7
    const int tile = blockIdx.x;   // 0..31 : kc = tile>>3, nc = tile&7
    const int l    = threadIdx.x;  // 0..63

    if (mat == 7){                 // bc = out_w @ bv + out_b (same fmaf order as r1-r16 fold)
        if (tile == 0){
            #pragma unroll
            for (int h = 0; h < 2; ++h){
                const int j = l + h * 64;
                float b = out_b[j];
                for (int k = 0; k < Hd; ++k)
                    b = fmaf(out_w[j * Hd + k], in_proj_b[2 * Hd + k], b);
                bc[j] = b;
            }
        }
        return;
    }

    const int kc = tile >> 3, nc = tile & 7;
    const int kbase = kc * 32 + (l >> 4) * 8;
    const int n = nc * 16 + (l & 15);
    const size_t obase = ((size_t)(mat * 32 + tile) * 64 + l) * 8;

    if (mat == 6){                 // fused fold: McT[ki][n] = sum_k out_w[n][k]*wv[k][ki]
        #pragma unroll
        for (int j = 0; j < 8; ++j){
            const int ki = kbase + j;
            float acc = 0.f;
            for (int k = 0; k < Hd; ++k)
                acc = fmaf(out_w[n * Hd + k], in_proj_w[(2 * Hd + k) * Hd + ki], acc);
            whi[obase + j] = f2bf(acc);
        }
        return;
    }

    const float* W;
    switch (mat){
        case 0: W = r_whh; break;  case 1: W = u_whh; break;
        case 2: W = r_wxh; break;  case 3: W = u_wxh; break;
        case 4: W = c_whh; break;  default: W = c_wxh;
    }
    #pragma unroll
    for (int j = 0; j < 8; ++j)
        whi[obase + j] = f2bf(W[(kbase + j) * Hd + n]);
}

#define MM1(acc, AH, BH)                                                  \
    acc = __builtin_amdgcn_mfma_f32_16x16x32_bf16(AH, BH, acc, 0, 0, 0);

// ===== gx precompute (double-buffered) + fused he_order tail blocks =====
__global__ __launch_bounds__(512, 1) void gx_he_kernel(
    const float* __restrict__ x_rank,
    const float* __restrict__ r_b, const float* __restrict__ u_b, const float* __restrict__ c_b,
    const unsigned short* __restrict__ whi,
    uint2* __restrict__ gx, int N, int NT, int gxblocks,
    const int* __restrict__ he_order, float* __restrict__ out_tail, int nv)
{
    const int tid = threadIdx.x;

    // he_order tail blocks: whole block branches off BEFORE any __syncthreads
    const int hb = (int)blockIdx.x - gxblocks;
    if (hb >= 0){
        const int i = hb * 512 + tid;
        if (i < nv) out_tail[i] = (float)he_order[i];
        return;
    }

    __shared__ __align__(16) unsigned short WX[2][16384];   // 64 KB -> 2 blocks/CU
    const int wid = tid >> 6;
    const int l   = tid & 63;
    const int lr  = l & 15;
    const int lg  = l >> 4;

    #define STAGE_X(mat, b)                                                      \
        {                                                                        \
            const unsigned short* msrc = whi + (size_t)(mat) * 16384;            \
            _Pragma("unroll")                                                    \
            for (int it = 0; it < 4; ++it){                                      \
                const int chunk = it * 8 + wid;                                  \
                gload_lds16(msrc + chunk * 512 + l * 8, &WX[b][chunk * 512]);    \
            }                                                                    \
        }

    STAGE_X(2, 0);                      // r_wxh -> buf0

    const int u = blockIdx.x * NW + wid;
    const int valid = (u < 3 * NT);
    const int uu = valid ? u : 3 * NT - 1;
    const int t  = uu / NT;
    const int nt = uu % NT;

    int nn = nt * NPW + lr; if (nn > N - 1) nn = N - 1;
    const float* xp = x_rank + ((size_t)nn * Rr + t) * Hd;
    s16x8 xh[4];
    #pragma unroll
    for (int kc = 0; kc < 4; ++kc)
        xh[kc] = cvt8(xp + kc * 32 + lg * 8);

    // g==0,t==0 is never read by rec9 (h0=0 path needs only gxu,gxc) -> skip store
    #define GX_COMP(g, b, bp)                                                    \
        {                                                                        \
            _Pragma("unroll")                                                    \
            for (int nc = 0; nc < 8; ++nc){                                      \
                f32x4 acc = (f32x4){0.f, 0.f, 0.f, 0.f};                         \
                _Pragma("unroll")                                                \
                for (int kc = 0; kc < 4; ++kc){                                  \
                    s16x8 bb = *(const s16x8*)&WX[b][(((kc) * 8 + nc) * 64 + l) * 8]; \
                    MM1(acc, xh[kc], bb);                                        \
                }                                                                \
                const float bv = bp[nc * 16 + lr];                               \
                uint2 o;                                                         \
                o.x = ((unsigned)f2bf(acc[1] + bv) << 16) | f2bf(acc[0] + bv);   \
                o.y = ((unsigned)f2bf(acc[3] + bv) << 16) | f2bf(acc[2] + bv);   \
                if (valid && ((g) != 0 || t != 0))                               \
                    gx[(((size_t)((g) * Rr + t) * NT + nt) * 8 + nc) * 64 + l] = o; \
                if ((nc & 3) == 3) __builtin_amdgcn_sched_barrier(0);            \
            }                                                                    \
        }

    __syncthreads();           // buf0 ready
    STAGE_X(3, 1);             // u_wxh -> buf1
    GX_COMP(0, 0, r_b);
    __syncthreads();           // buf1 ready; buf0 readers done
    STAGE_X(5, 0);             // c_wxh -> buf0
    GX_COMP(1, 1, u_b);
    __syncthreads();           // buf0 ready
    GX_COMP(2, 0, c_b);
    #undef GX_COMP
    #undef STAGE_X
}

// ===== 9-phase recurrent kernel (r15-proven structure + gx prefetch) =====
#define BF_LDS(kc, nc) (*(const s16x8*)&WL[cur][(((kc) * 8 + (nc)) * 64 + l) * 8])
#define GXLD(g, t, nc) gx[(((size_t)((g) * Rr + (t)) * NT + gtile) * 8 + (nc)) * 64 + l]

__global__ __launch_bounds__(512, 1) void gru_rec9_kernel(
    const int* __restrict__ valid_idx, int nv,
    const unsigned short* __restrict__ whi,
    const uint2* __restrict__ gx,
    const float* __restrict__ bc,
    float* __restrict__ out, int N, int NT)
{
    __shared__ __align__(16) unsigned short WL[2][16384];   // 64 KB double buffer
    __shared__ __align__(16) float Sr_all[NW][NPW][132];    // 67.6 KB fp32 (proven)
    __shared__ int lo_all[NW][NPW];
    __shared__ int hi_all[NW][NPW];

    const int tid = threadIdx.x;
    const int wid = tid >> 6;
    const int l   = tid & 63;
    const int lr  = l & 15;
    const int lg  = l >> 4;
    const int wtile = blockIdx.x * NW + wid;
    const int n0  = wtile * NPW;
    const int gtile = (wtile < NT) ? wtile : NT - 1;   // OOB waves clamp; rows never stored

    float (*Sr)[132] = Sr_all[wid];
    int* loL = lo_all[wid];
    int* hiL = hi_all[wid];

    #define STAGE_MAT(mat, b)                                                    \
        {                                                                        \
            const unsigned short* msrc = whi + (size_t)(mat) * 16384;            \
            _Pragma("unroll")                                                    \
            for (int it = 0; it < 4; ++it){                                      \
                const int chunk = it * 8 + wid;                                  \
                gload_lds16(msrc + chunk * 512 + l * 8, &WL[b][chunk * 512]);    \
            }                                                                    \
        }

    f32x4 hD[8];
    s16x8 ah[4], rhh[4];
    f32x4 zD[8];
    float obc[8];
    #pragma unroll
    for (int nc = 0; nc < 8; ++nc) obc[nc] = bc[nc * 16 + lr];

    unsigned cur = 0;
    STAGE_MAT(6, 0);          // prologue: McT into buf0

    #pragma unroll 1
    for (int t = 0; t < Rr; ++t){
        // ---- output-row ranges ----
        if (l < NPW){
            int n = n0 + l, lo = 0, hi = 0;
            if (n < N){
                int F = (n * Rr + t) * Ll;
                lo = lower_bound_i32(valid_idx, nv, F);
                hi = lower_bound_i32(valid_idx, nv, F + Ll);
            }
            loL[l] = lo; hiL[l] = hi;
        }

        if (t == 0){
            // h0 = 0: z = sig(gxu), c = tanh(gxc), h1 = z*c  (pure VALU, pre-barrier)
            uint2 gu[8], gc[8];
            #pragma unroll
            for (int nc = 0; nc < 8; ++nc){ gu[nc] = GXLD(1, 0, nc); gc[nc] = GXLD(2, 0, nc); }
            #pragma unroll
            for (int nc = 0; nc < 8; ++nc){
                #pragma unroll
                for (int i = 0; i < 4; ++i){
                    float z = 1.f / (1.f + __expf(-gxel(gu[nc], i)));
                    float e = __expf(2.f * gxel(gc[nc], i));
                    float c = 1.f - 2.f / (e + 1.f);
                    float hn = z * c;
                    hD[nc][i] = hn;
                    Sr[lg * 4 + i][nc * 16 + lr] = hn;
                }
            }
            #pragma unroll
            for (int kc = 0; kc < 4; ++kc)
                ah[kc] = cvt8(&Sr[lr][kc * 32 + lg * 8]);
        } else {
            // ---- prefetch ALL gx addends for this t (issued before S1's barrier;
            //      latency hides under S1/S2 phases) ----
            uint2 gr[8], gu[8], gc[8];
            #pragma unroll
            for (int nc = 0; nc < 8; ++nc){
                gr[nc] = GXLD(0, t, nc);
                gu[nc] = GXLD(1, t, nc);
                gc[nc] = GXLD(2, t, nc);
            }

            // ==== S1: [r_whh ready] issue u_whh; accR = h@r_whh + gxr; Sr = r*h ====
            __syncthreads();
            STAGE_MAT(1, cur ^ 1);
            #pragma unroll
            for (int nc = 0; nc < 8; ++nc){
                f32x4 accR = (f32x4){0.f, 0.f, 0.f, 0.f};
                #pragma unroll
                for (int kc = 0; kc < 4; ++kc){ s16x8 b = BF_LDS(kc, nc); MM1(accR, ah[kc], b); }
                #pragma unroll
                for (int i = 0; i < 4; ++i){
                    float r = 1.f / (1.f + __expf(-(accR[i] + gxel(gr[nc], i))));
                    Sr[lg * 4 + i][nc * 16 + lr] = r * hD[nc][i];
                }
                if ((nc & 3) == 3) __builtin_amdgcn_sched_barrier(0);
            }
            cur ^= 1;

            // ==== S2: [u_whh ready] issue c_whh; z = sig(h@u_whh + gxu); rh frags ====
            __syncthreads();
            STAGE_MAT(4, cur ^ 1);
            #pragma unroll
            for (int nc = 0; nc < 8; ++nc){
                f32x4 accZ = (f32x4){0.f, 0.f, 0.f, 0.f};
                #pragma unroll
                for (int kc = 0; kc < 4; ++kc){ s16x8 b = BF_LDS(kc, nc); MM1(accZ, ah[kc], b); }
                #pragma unroll
                for (int i = 0; i < 4; ++i)
                    zD[nc][i] = 1.f / (1.f + __expf(-(accZ[i] + gxel(gu[nc], i))));
                if ((nc & 3) == 3) __builtin_amdgcn_sched_barrier(0);
            }
            #pragma unroll
            for (int kc = 0; kc < 4; ++kc)
                rhh[kc] = cvt8(&Sr[lr][kc * 32 + lg * 8]);
            cur ^= 1;

            // ==== S3: [c_whh ready] issue McT; c = tanh(rh@c_whh + gxc); h update ====
            __syncthreads();
            STAGE_MAT(6, cur ^ 1);
            #pragma unroll
            for (int nc = 0; nc < 8; ++nc){
                f32x4 accC = (f32x4){0.f, 0.f, 0.f, 0.f};
                #pragma unroll
                for (int kc = 0; kc < 4; ++kc){ s16x8 b = BF_LDS(kc, nc); MM1(accC, rhh[kc], b); }
                #pragma unroll
                for (int i = 0; i < 4; ++i){
                    float e = __expf(2.f * (accC[i] + gxel(gc[nc], i)));
                    float c = 1.f - 2.f / (e + 1.f);
                    float ho = hD[nc][i];
                    float hn = ho + zD[nc][i] * (c - ho);
                    hD[nc][i] = hn;
                    Sr[lg * 4 + i][nc * 16 + lr] = hn;
                }
                if ((nc & 3) == 3) __builtin_amdgcn_sched_barrier(0);
            }
            #pragma unroll
            for (int kc = 0; kc < 4; ++kc)
                ah[kc] = cvt8(&Sr[lr][kc * 32 + lg * 8]);
            cur ^= 1;
        }

        // ==== O: [McT ready] issue next-t r_whh; accO = h'@McT + bc; scatter ====
        __syncthreads();
        if (t < Rr - 1) STAGE_MAT(0, cur ^ 1);
        #pragma unroll
        for (int nc = 0; nc < 8; ++nc){
            f32x4 ao = (f32x4){0.f, 0.f, 0.f, 0.f};
            #pragma unroll
            for (int kc = 0; kc < 4; ++kc){ s16x8 b = BF_LDS(kc, nc); MM1(ao, ah[kc], b); }
            #pragma unroll
            for (int i = 0; i < 4; ++i)
                Sr[lg * 4 + i][nc * 16 + lr] = ao[i] + obc[nc];
            if ((nc & 3) == 3) __builtin_amdgcn_sched_barrier(0);
        }
        // epilogue: 32 lanes cover one 512-B out row; own-wave Sr (in-order)
        #pragma unroll
        for (int m = 0; m < 8; ++m){
            const int row = m * 2 + (l >> 5);
            const int c4  = (l & 31) * 4;
            const float4 v = *(const float4*)&Sr[row][c4];
            const int lo = loL[row], hi = hiL[row];
            for (int rr = lo; rr < hi; ++rr)
                *(float4*)(out + (size_t)rr * Hd + c4) = v;
        }
        cur ^= 1;
    }
    #undef STAGE_MAT
}

// ================= fallback: round-9 kernel (used if ws_size too small) =================
__global__ __launch_bounds__(512, 1) void gru_mfma_fb(
    const float* __restrict__ x_rank,
    const int* __restrict__ valid_idx, int nv,
    const float* __restrict__ r_b, const float* __restrict__ u_b, const float* __restrict__ c_b,
    const unsigned short* __restrict__ whi,
    const float* __restrict__ bc,
    float* __restrict__ out, int N)
{
    __shared__ __align__(16) unsigned short WL[2][16384];
    __shared__ __align__(16) float Sr_all[NW][NPW][132];
    __shared__ float bias_s[4][Hd];
    __shared__ int lo_all[NW][NPW];
    __shared__ int hi_all[NW][NPW];

    const int tid = threadIdx.x;
    const int wid = tid >> 6;
    const int l   = tid & 63;
    const int lr  = l & 15;
    const int lg  = l >> 4;
    const int n0  = (blockIdx.x * NW + wid) * NPW;

    float (*Sr)[132] = Sr_all[wid];
    int* loL = lo_all[wid];
    int* hiL = hi_all[wid];

    if (tid < Hd){
        bias_s[0][tid] = r_b[tid];
        bias_s[1][tid] = u_b[tid];
        bias_s[2][tid] = c_b[tid];
        bias_s[3][tid] = bc[tid];
    }
    #define STAGE_MAT(mat, b)                                                    \
        {                                                                        \
            const unsigned short* msrc = whi + (size_t)(mat) * 16384;            \
            _Pragma("unroll")                                                    \
            for (int it = 0; it < 4; ++it){                                      \
                const int chunk = it * 8 + wid;                                  \
                gload_lds16(msrc + chunk * 512 + l * 8, &WL[b][chunk * 512]);    \
            }                                                                    \
        }
    f32x4 hD[8];
    s16x8 ah[4];
    #pragma unroll
    for (int nc = 0; nc < 8; ++nc) hD[nc] = (f32x4){0.f, 0.f, 0.f, 0.f};
    #pragma unroll
    for (int kc = 0; kc < 4; ++kc) ah[kc] = (s16x8)0;
    s16x8 xh[4], rhh[4];

    unsigned cur = 0;
    STAGE_MAT(0, 0);

    #pragma unroll 1
    for (int t = 0; t < Rr; ++t){
        if (l < NPW){
            int n = n0 + l, lo = 0, hi = 0;
            if (n < N){
                int F = (n * Rr + t) * Ll;
                lo = lower_bound_i32(valid_idx, nv, F);
                hi = lower_bound_i32(valid_idx, nv, F + Ll);
            }
            loL[l] = lo; hiL[l] = hi;
        }
        {
            int nn = n0 + lr; if (nn > N - 1) nn = N - 1;
            const float* xp = x_rank + ((size_t)nn * Rr + t) * Hd;
            #pragma unroll
            for (int kc = 0; kc < 4; ++kc)
                xh[kc] = cvt8(xp + kc * 32 + lg * 8);
        }
        f32x4 accR[8], accZ[8];
        __syncthreads();
        STAGE_MAT(2, cur ^ 1);
        #pragma unroll
        for (int nc = 0; nc < 8; ++nc){
            accR[nc] = (f32x4){0.f, 0.f, 0.f, 0.f};
            #pragma unroll
            for (int kc = 0; kc < 4; ++kc){ s16x8 b = BF_LDS(kc, nc); MM1(accR[nc], ah[kc], b); }
            if ((nc & 3) == 3) __builtin_amdgcn_sched_barrier(0);
        }
        cur ^= 1;
        __syncthreads();
        STAGE_MAT(1, cur ^ 1);
        #pragma unroll
        for (int nc = 0; nc < 8; ++nc){
            #pragma unroll
            for (int kc = 0; kc < 4; ++kc){ s16x8 b = BF_LDS(kc, nc); MM1(accR[nc], xh[kc], b); }
            const float rbc = bias_s[0][nc * 16 + lr];
            #pragma unroll
            for (int i = 0; i < 4; ++i){
                float r = 1.f / (1.f + __expf(-(accR[nc][i] + rbc)));
                Sr[lg * 4 + i][nc * 16 + lr] = r * hD[nc][i];
            }
            if ((nc & 3) == 3) __builtin_amdgcn_sched_barrier(0);
        }
        cur ^= 1;
        __syncthreads();
        STAGE_MAT(3, cur ^ 1);
        #pragma unroll
        for (int nc = 0; nc < 8; ++nc){
            accZ[nc] = (f32x4){0.f, 0.f, 0.f, 0.f};
            #pragma unroll
            for (int kc = 0; kc < 4; ++kc){ s16x8 b = BF_LDS(kc, nc); MM1(accZ[nc], ah[kc], b); }
            if ((nc & 3) == 3) __builtin_amdgcn_sched_barrier(0);
        }
        cur ^= 1;
        __syncthreads();
        STAGE_MAT(4, cur ^ 1);
        #pragma unroll
        for (int nc = 0; nc < 8; ++nc){
            #pragma unroll
            for (int kc = 0; kc < 4; ++kc){ s16x8 b = BF_LDS(kc, nc); MM1(accZ[nc], xh[kc], b); }
            const float ubc = bias_s[1][nc * 16 + lr];
            #pragma unroll
            for (int i = 0; i < 4; ++i)
                accZ[nc][i] = 1.f / (1.f + __expf(-(accZ[nc][i] + ubc)));
            if ((nc & 3) == 3) __builtin_amdgcn_sched_barrier(0);
        }
        cur ^= 1;
        __syncthreads();
        STAGE_MAT(5, cur ^ 1);
        #pragma unroll
        for (int kc = 0; kc < 4; ++kc)
            rhh[kc] = cvt8(&Sr[lr][kc * 32 + lg * 8]);
        f32x4 accC[8];
        #pragma unroll
        for (int nc = 0; nc < 8; ++nc){
            accC[nc] = (f32x4){0.f, 0.f, 0.f, 0.f};
            #pragma unroll
            for (int kc = 0; kc < 4; ++kc){ s16x8 b = BF_LDS(kc, nc); MM1(accC[nc], rhh[kc], b); }
            if ((nc & 3) == 3) __builtin_amdgcn_sched_barrier(0);
        }
        cur ^= 1;
        __syncthreads();
        STAGE_MAT(6, cur ^ 1);
        #pragma unroll
        for (int nc = 0; nc < 8; ++nc){
            #pragma unroll
            for (int kc = 0; kc < 4; ++kc){ s16x8 b = BF_LDS(kc, nc); MM1(accC[nc], xh[kc], b); }
            const float cbc = bias_s[2][nc * 16 + lr];
            #pragma unroll
            for (int i = 0; i < 4; ++i){
                float e = __expf(2.f * (accC[nc][i] + cbc));
                float c = 1.f - 2.f / (e + 1.f);
                float ho = hD[nc][i];
                float hn = ho + accZ[nc][i] * (c - ho);
                hD[nc][i] = hn;
                Sr[lg * 4 + i][nc * 16 + lr] = hn;
            }
            if ((nc & 3) == 3) __builtin_amdgcn_sched_barrier(0);
        }
        #pragma unroll
        for (int kc = 0; kc < 4; ++kc)
            ah[kc] = cvt8(&Sr[lr][kc * 32 + lg * 8]);
        cur ^= 1;
        __syncthreads();
        if (t < Rr - 1) STAGE_MAT(0, cur ^ 1);
        #pragma unroll
        for (int nc = 0; nc < 8; ++nc){
            f32x4 ao = (f32x4){0.f, 0.f, 0.f, 0.f};
            #pragma unroll
            for (int kc = 0; kc < 4; ++kc){ s16x8 b = BF_LDS(kc, nc); MM1(ao, ah[kc], b); }
            const float obc = bias_s[3][nc * 16 + lr];
            #pragma unroll
            for (int i = 0; i < 4; ++i)
                Sr[lg * 4 + i][nc * 16 + lr] = ao[i] + obc;
            if ((nc & 3) == 3) __builtin_amdgcn_sched_barrier(0);
        }
        #pragma unroll
        for (int m = 0; m < 8; ++m){
            const int row = m * 2 + (l >> 5);
            const int c4  = (l & 31) * 4;
            const float4 v = *(const float4*)&Sr[row][c4];
            const int lo = loL[row], hi = hiL[row];
            for (int rr = lo; rr < hi; ++rr)
                *(float4*)(out + (size_t)rr * Hd + c4) = v;
        }
        cur ^= 1;
    }
    #undef STAGE_MAT
}

__global__ void he_order_kernel(const int* __restrict__ he_order,
                                float* __restrict__ out_tail, int nv)
{
    const int i = blockIdx.x * 256 + threadIdx.x;
    if (i < nv) out_tail[i] = (float)he_order[i];
}

extern "C" void kernel_launch(void* const* d_in, const int* in_sizes, int n_in,
                              void* d_out, int out_size, void* d_ws, size_t ws_size,
                              hipStream_t stream)
{
    const float* x_rank    = (const float*)d_in[0];
    // d_in[1] he_features, d_in[2] he_idx: dead (softmax over singleton axis == 1)
    const int*   valid_idx = (const int*)d_in[3];
    const int*   he_order  = (const int*)d_in[4];
    const float* r_whh = (const float*)d_in[5];
    const float* r_wxh = (const float*)d_in[6];
    const float* r_b   = (const float*)d_in[7];
    const float* u_whh = (const float*)d_in[8];
    const float* u_wxh = (const float*)d_in[9];
    const float* u_b   = (const float*)d_in[10];
    const float* c_whh = (const float*)d_in[11];
    const float* c_wxh = (const float*)d_in[12];
    const float* c_b   = (const float*)d_in[13];
    const float* in_proj_w = (const float*)d_in[14];
    const float* in_proj_b = (const float*)d_in[15];
    const float* out_w     = (const float*)d_in[16];
    const float* out_b     = (const float*)d_in[17];

    const int nv = in_sizes[3];
    const int N  = in_sizes[0] / (Rr * Hd);
    const int NT = (N + NPW - 1) / NPW;   // 1875

    // workspace layout: [bc 512 B][whi 229376 B][pad][gx 69.12 MB]
    float* bc = (float*)d_ws;
    unsigned short* whi = (unsigned short*)(bc + 128);
    const size_t base = ((size_t)128 * 4 + 7 * 16384 * 2 + 255) & ~(size_t)255;
    uint2* gx = (uint2*)((char*)d_ws + base);
    const size_t gx_bytes = (size_t)9 * NT * 8 * 64 * 8;

    float* out_f    = (float*)d_out;
    float* out_tail = out_f + (size_t)nv * Hd;

    pack_kernel<<<dim3(32, 8), 64, 0, stream>>>(
        r_whh, u_whh, r_wxh, u_wxh, c_whh, c_wxh,
        in_proj_w, in_proj_b, out_w, out_b, whi, bc);

    const int nodes_per_block = NW * NPW;  // 128
    const int nblocks = (N + nodes_per_block - 1) / nodes_per_block;  // 235

    if (ws_size >= base + gx_bytes){
        const int gxb = (3 * NT + NW - 1) / NW;   // 704
        const int heb = (nv + 511) / 512;
        gx_he_kernel<<<gxb + heb, 512, 0, stream>>>(
            x_rank, r_b, u_b, c_b, whi, gx, N, NT, gxb, he_order, out_tail, nv);
        gru_rec9_kernel<<<nblocks, 512, 0, stream>>>(valid_idx, nv, whi, gx, bc, out_f, N, NT);
    } else {
        gru_mfma_fb<<<nblocks, 512, 0, stream>>>(
            x_rank, valid_idx, nv, r_b, u_b, c_b, whi, bc, out_f, N);
        he_order_kernel<<<(nv + 255) / 256, 256, 0, stream>>>(he_order, out_tail, nv);
    }
}